// Round 7
// baseline (207.357 us; speedup 1.0000x reference)
//
#include <hip/hip_runtime.h>
#include <hip/hip_bf16.h>

#define NPX 16384
typedef __attribute__((ext_vector_type(8))) short short8;
typedef __attribute__((ext_vector_type(8))) _Float16 half8;
typedef __attribute__((ext_vector_type(4))) float f32x4;

#define DEV static __device__ __forceinline__

// wt layout (fp16 shorts)
#define WAB   0
#define WINW  4096
#define W1T   8192
#define W2T   16384
#define W3T   32768
#define WQT   40960
#define WKV   45056
#define WTOT  53248

DEV float lrelu(float v) { return v >= 0.f ? v : 0.01f * v; }
DEV short f2h(float f) { _Float16 h = (_Float16)f; return __builtin_bit_cast(short, h); }
DEV float h2f(short s) { return (float)__builtin_bit_cast(_Float16, s); }
DEV f32x4 mfmah(half8 a, half8 b, f32x4 c) {
    return __builtin_amdgcn_mfma_f32_16x16x32_f16(a, b, c, 0, 0, 0);
}

// ---------------------------------------------------------------------------
// M m-tiles (16 px each) GEMM: acc[m][t] += A[(m*16+row)][k] * WT[t*16+col][k]
// ---------------------------------------------------------------------------
template<int K, int NT, int M>
DEV void gemmM(const short* __restrict__ A, int pitch,
               const short* __restrict__ WT, f32x4 (&acc)[M][NT])
{
    int lane = threadIdx.x & 63;
    int ln = lane & 15, q8 = (lane >> 4) * 8;
    const short* bp = WT + ln * K + q8;
#pragma unroll
    for (int c0 = 0; c0 < K; c0 += 32) {
        half8 a[M];
#pragma unroll
        for (int m = 0; m < M; ++m)
            a[m] = *(const half8*)(A + (size_t)(m * 16 + ln) * pitch + q8 + c0);
#pragma unroll
        for (int t = 0; t < NT; ++t) {
            half8 b = *(const half8*)(bp + (size_t)t * 16 * K + c0);
#pragma unroll
            for (int m = 0; m < M; ++m) acc[m][t] = mfmah(a[m], b, acc[m][t]);
        }
    }
}

template<int NT, int M>
DEV void acc_biasM(f32x4 (&acc)[M][NT], const float* __restrict__ bias)
{
    int ln = threadIdx.x & 15;
#pragma unroll
    for (int t = 0; t < NT; ++t) {
        float bv = bias[t * 16 + ln];
        f32x4 v = {bv, bv, bv, bv};
#pragma unroll
        for (int m = 0; m < M; ++m) acc[m][t] = v;
    }
}

// D layout: col=lane&15, row=(lane>>4)*4+reg -> LDS [m*16+row][pitch] fp16
template<int NT, int M>
DEV void dstoreM(const f32x4 (&acc)[M][NT], short* sD, int pitch)
{
    int lane = threadIdx.x & 63;
    int ln = lane & 15, r0 = (lane >> 4) * 4;
#pragma unroll
    for (int m = 0; m < M; ++m)
#pragma unroll
        for (int t = 0; t < NT; ++t)
#pragma unroll
            for (int r = 0; r < 4; ++r)
                sD[(m * 16 + r0 + r) * pitch + t * 16 + ln] = f2h(acc[m][t][r]);
}

// in-register LayerNorm(+lrelu) over 128 channels, fp32 stats
template<int NT, int M>
DEV void ln_regM(f32x4 (&acc)[M][NT], const float* __restrict__ g, const float* __restrict__ be)
{
    int lane = threadIdx.x & 63, ln = lane & 15;
#pragma unroll
    for (int m = 0; m < M; ++m) {
        f32x4 s = {0,0,0,0}, ss = {0,0,0,0};
#pragma unroll
        for (int t = 0; t < NT; ++t)
#pragma unroll
            for (int r = 0; r < 4; ++r) { float v = acc[m][t][r]; s[r] += v; ss[r] += v * v; }
#pragma unroll
        for (int off = 1; off < 16; off <<= 1)
#pragma unroll
            for (int r = 0; r < 4; ++r) {
                s[r] += __shfl_xor(s[r], off);
                ss[r] += __shfl_xor(ss[r], off);
            }
        f32x4 mm, rs;
#pragma unroll
        for (int r = 0; r < 4; ++r) {
            float mean = s[r] * (1.f / 128.f);
            float var = ss[r] * (1.f / 128.f) - mean * mean;
            mm[r] = mean; rs[r] = rsqrtf(var + 1e-5f);
        }
#pragma unroll
        for (int t = 0; t < NT; ++t) {
            float gg = g[t * 16 + ln], bb = be[t * 16 + ln];
#pragma unroll
            for (int r = 0; r < 4; ++r)
                acc[m][t][r] = lrelu((acc[m][t][r] - mm[r]) * rs[r] * gg + bb);
        }
    }
}

// wave-level copyout of ROWSx64 fp16 tile -> global [px][64]
template<int ROWS>
DEV void copyoutR(const short* sD, int pitch, short* __restrict__ dst)
{
    int lane = threadIdx.x & 63;
#pragma unroll
    for (int it = 0; it < ROWS / 8; ++it) {
        int idx = it * 512 + lane * 8;
        int px = idx >> 6, c = idx & 63;
        short8 v = *(const short8*)(&sD[px * pitch + c]);
        *reinterpret_cast<short8*>(dst + (size_t)px * 64 + c) = v;
    }
}

// stage 16 px of x (fp32 channel-major) -> wave LDS [16][72] fp16
DEV void stage_x16(const float* __restrict__ xb, int n0, short* X)
{
    int lane = threadIdx.x & 63;
    int ln = lane & 15, qd = lane >> 4;
    float vb[16];
#pragma unroll
    for (int t = 0; t < 16; ++t) vb[t] = xb[(size_t)(qd * 16 + t) * NPX + n0 + ln];
    short8 lo, hi;
#pragma unroll
    for (int t = 0; t < 8; ++t) { lo[t] = f2h(vb[t]); hi[t] = f2h(vb[8 + t]); }
    *reinterpret_cast<short8*>(&X[ln * 72 + qd * 16]) = lo;
    *reinterpret_cast<short8*>(&X[ln * 72 + qd * 16 + 8]) = hi;
}

// ---------------------------------------------------------------------------
// k_prep: transposed fp16 weights WT[e][k]
// ---------------------------------------------------------------------------
__global__ __launch_bounds__(256) void k_prep(const float* __restrict__ wa,
                                              const float* __restrict__ wb,
                                              const float* __restrict__ in_w,
                                              const float* __restrict__ w1,
                                              const float* __restrict__ w2,
                                              const float* __restrict__ w3,
                                              const float* __restrict__ wq,
                                              const float* __restrict__ wk,
                                              const float* __restrict__ wv,
                                              short* __restrict__ wt)
{
    int idx = blockIdx.x * 256 + threadIdx.x;
    if (idx >= WTOT) return;
    float v;
    if (idx < WINW) {
        int j = idx >> 6, c = idx & 63;
        v = (j < 4) ? wa[c * 4 + j] : wb[((j - 4) / 3) * 192 + c * 3 + ((j - 4) % 3)];
    } else if (idx < W1T) {
        int i = idx - WINW; v = in_w[(i & 63) * 64 + (i >> 6)];
    } else if (idx < W2T) {
        int i = idx - W1T; v = w1[(i & 63) * 128 + (i >> 6)];
    } else if (idx < W3T) {
        int i = idx - W2T; v = w2[(i & 127) * 128 + (i >> 7)];
    } else if (idx < WQT) {
        int i = idx - W3T; v = w3[(i & 127) * 64 + (i >> 7)];
    } else if (idx < WKV) {
        int i = idx - WQT; v = wq[(i & 63) * 64 + (i >> 6)];
    } else {
        int i = idx - WKV; int e = i >> 6, k = i & 63;
        v = (e < 64) ? wk[k * 64 + e] : wv[k * 64 + (e - 64)];
    }
    wt[idx] = f2h(v);
}

// ---------------------------------------------------------------------------
// k_main: x,sem -> {k,v} (fyk chain) and {xm,q} (mlp chain), interleaved.
// 16 px/wave, barrier-free, per-wave LDS buffers X/F/S with reuse.
// ---------------------------------------------------------------------------
__global__ __launch_bounds__(256) void k_main(const float* __restrict__ x,
                                              const float* __restrict__ sem,
                                              const float* __restrict__ ba,
                                              const float* __restrict__ bbv,
                                              const float* __restrict__ in_b,
                                              const float* __restrict__ bk,
                                              const float* __restrict__ bv,
                                              const float* __restrict__ b1,
                                              const float* __restrict__ g1,
                                              const float* __restrict__ be1,
                                              const float* __restrict__ b2,
                                              const float* __restrict__ g2,
                                              const float* __restrict__ be2,
                                              const float* __restrict__ b3,
                                              const float* __restrict__ bq,
                                              const short* __restrict__ wt,
                                              short* __restrict__ kout,
                                              short* __restrict__ vout,
                                              short* __restrict__ xmout,
                                              short* __restrict__ qout)
{
    __shared__ short sX[4][16 * 72];
    __shared__ short sF[4][16 * 72];
    __shared__ short sS[4][16 * 136];
    int tid = threadIdx.x, w = tid >> 6, lane = tid & 63;
    int ln = lane & 15, qd = lane >> 4, r0 = qd * 4;
    int pw = blockIdx.x * 64 + w * 16;
    int b = pw >> 14, n0 = pw & (NPX - 1);
    const float* xb = x + (size_t)b * 64 * NPX;
    short* X = sX[w];
    short* F = sF[w];
    short* S = sS[w];

    stage_x16(xb, n0, X);

    // two independent gemms on X (ILP across chains)
    f32x4 ah1[1][8];
    acc_biasM<8, 1>(ah1, b1);
    gemmM<64, 8, 1>(X, 72, wt + W1T, ah1);
    f32x4 af[1][4];
    { f32x4 z = {0,0,0,0}; for (int t = 0; t < 4; ++t) af[0][t] = z; }
    gemmM<64, 4, 1>(X, 72, wt + WAB, af);

    // feat epilogue: relu(sem[class]) * acc + bias -> F
#pragma unroll
    for (int t = 0; t < 4; ++t) {
        int j = t * 16 + ln;
        int cls = (j < 4) ? 0 : 1 + (j - 4) / 3;
        float bias = (j < 4) ? ba[j] : bbv[j - 4];
        f32x4 sm4 = *(const f32x4*)(sem + ((size_t)b * 21 + cls) * NPX + n0 + r0);
#pragma unroll
        for (int r = 0; r < 4; ++r)
            F[(r0 + r) * 72 + j] = f2h(fmaxf(sm4[r], 0.f) * af[0][t][r] + bias);
    }
    // h1 = lrelu(LN(..)) -> S
    ln_regM<8, 1>(ah1, g1, be1);
    dstoreM<8, 1>(ah1, S, 136);

    // y = feat @ in_w (F->F) ; h2 = h1 @ w2 (S->S)  — independent
    f32x4 ay[1][4];
    acc_biasM<4, 1>(ay, in_b);
    gemmM<64, 4, 1>(F, 72, wt + WINW, ay);
    f32x4 ah2[1][8];
    acc_biasM<8, 1>(ah2, b2);
    gemmM<128, 8, 1>(S, 136, wt + W2T, ah2);
    dstoreM<4, 1>(ay, F, 72);
    ln_regM<8, 1>(ah2, g2, be2);
    dstoreM<8, 1>(ah2, S, 136);

    // kv = y @ [wk|wv] (F) ; xm = h2 @ w3 (S)  — independent
    f32x4 akv[1][8];
    {
#pragma unroll
        for (int t = 0; t < 8; ++t) {
            float bvv = (t < 4) ? bk[t * 16 + ln] : bv[(t - 4) * 16 + ln];
            f32x4 vv = {bvv, bvv, bvv, bvv};
            akv[0][t] = vv;
        }
    }
    gemmM<64, 8, 1>(F, 72, wt + WKV, akv);
    f32x4 axm[1][4];
    acc_biasM<4, 1>(axm, b3);
    gemmM<128, 4, 1>(S, 136, wt + W3T, axm);

    // k out (F), then v out (F reused; in-order DS makes this safe)
#pragma unroll
    for (int t = 0; t < 4; ++t)
#pragma unroll
        for (int r = 0; r < 4; ++r)
            F[(r0 + r) * 72 + t * 16 + ln] = f2h(akv[0][t][r]);
    copyoutR<16>(F, 72, kout + (size_t)pw * 64);
#pragma unroll
    for (int t = 0; t < 4; ++t)
#pragma unroll
        for (int r = 0; r < 4; ++r)
            F[(r0 + r) * 72 + t * 16 + ln] = f2h(akv[0][t + 4][r]);
    copyoutR<16>(F, 72, vout + (size_t)pw * 64);

    // xm out via X (x dead), then q = xm @ wq
    dstoreM<4, 1>(axm, X, 72);
    copyoutR<16>(X, 72, xmout + (size_t)pw * 64);
    f32x4 aq[1][4];
    acc_biasM<4, 1>(aq, bq);
    gemmM<64, 4, 1>(X, 72, wt + WQT, aq);
    dstoreM<4, 1>(aq, F, 72);
    copyoutR<16>(F, 72, qout + (size_t)pw * 64);
}

// ---------------------------------------------------------------------------
// k_gram: per-wave 128-px chunk; 3 MFMAs (qk, qq, kk); fp32 atomics
// ---------------------------------------------------------------------------
__global__ __launch_bounds__(256) void k_gram(const short* __restrict__ q,
                                              const short* __restrict__ k,
                                              float* __restrict__ gram,
                                              float* __restrict__ nsq)
{
    __shared__ short sQ[4][16 * 136], sK[4][16 * 136];
    int tid = threadIdx.x, w = tid >> 6, lane = tid & 63;
    int ln = lane & 15, q8 = (lane >> 4) * 8, qd = lane >> 4;
    int bh = blockIdx.x >> 5;
    int b = bh >> 2, h = bh & 3;
    int nb = (blockIdx.x & 31) * 512 + w * 128;
    size_t pxg = (size_t)b * NPX + nb;

#pragma unroll
    for (int it = 0; it < 4; ++it) {
        int idx = it * 64 + lane;
        int px = idx >> 1, half = idx & 1;
        short8 qv = *(const short8*)(q + (pxg + px) * 64 + h * 16 + half * 8);
        short8 kv = *(const short8*)(k + (pxg + px) * 64 + h * 16 + half * 8);
#pragma unroll
        for (int j = 0; j < 8; ++j) {
            sQ[w][(half * 8 + j) * 136 + px] = qv[j];
            sK[w][(half * 8 + j) * 136 + px] = kv[j];
        }
    }

    f32x4 aqk = {0,0,0,0}, aqq = {0,0,0,0}, akk = {0,0,0,0};
#pragma unroll
    for (int s = 0; s < 4; ++s) {
        half8 a  = *(const half8*)(&sQ[w][ln * 136 + s * 32 + q8]);
        half8 bb = *(const half8*)(&sK[w][ln * 136 + s * 32 + q8]);
        aqk = mfmah(a, bb, aqk);
        aqq = mfmah(a, a, aqq);
        akk = mfmah(bb, bb, akk);
    }
    int e = ln;
#pragma unroll
    for (int r = 0; r < 4; ++r) {
        int d = qd * 4 + r;
        atomicAdd(&gram[bh * 256 + d * 16 + e], aqk[r]);
        if (e == d) {
            atomicAdd(&nsq[bh * 16 + d], aqq[r]);
            atomicAdd(&nsq[256 + bh * 16 + d], akk[r]);
        }
    }
}

// ---------------------------------------------------------------------------
// k_attnM: softmax + fold wo -> MT[b][cc][he] fp16
// ---------------------------------------------------------------------------
__global__ __launch_bounds__(256) void k_attnM(const float* __restrict__ gram,
                                               const float* __restrict__ nsq,
                                               const float* __restrict__ rescale,
                                               const float* __restrict__ wo,
                                               short* __restrict__ MT)
{
    __shared__ float s_at[1024];
    int b = blockIdx.x, tid = threadIdx.x;
    if (tid < 64) {
        int h = tid >> 4, d = tid & 15;
        float nq = sqrtf(nsq[b * 64 + h * 16 + d]) + 1e-8f;
        float rsc = rescale[h];
        float lg[16];
#pragma unroll
        for (int e = 0; e < 16; ++e) {
            float nk = sqrtf(nsq[256 + b * 64 + h * 16 + e]) + 1e-8f;
            lg[e] = rsc * gram[b * 1024 + h * 256 + d * 16 + e] / (nq * nk);
        }
        float m = lg[0];
#pragma unroll
        for (int e = 1; e < 16; ++e) m = fmaxf(m, lg[e]);
        float ssum = 0.f;
#pragma unroll
        for (int e = 0; e < 16; ++e) { lg[e] = expf(lg[e] - m); ssum += lg[e]; }
        float inv = 1.f / ssum;
#pragma unroll
        for (int e = 0; e < 16; ++e) s_at[h * 256 + d * 16 + e] = lg[e] * inv;
    }
    __syncthreads();
    int he = tid >> 2, h = he >> 4, e = he & 15;
    int cc0 = (tid & 3) * 16;
#pragma unroll
    for (int cx = 0; cx < 16; ++cx) {
        int cc = cc0 + cx;
        float s = 0.f;
#pragma unroll
        for (int d = 0; d < 16; ++d)
            s = fmaf(s_at[h * 256 + d * 16 + e], wo[(h * 16 + d) * 64 + cc], s);
        MT[b * 4096 + cc * 64 + he] = f2h(s);
    }
}

// ---------------------------------------------------------------------------
// k_out: out[b][c][n] = v@M + bo + xm   (barrier-free, no LDS, 16 px/wave)
// ---------------------------------------------------------------------------
__global__ __launch_bounds__(256) void k_out(const short* __restrict__ v,
                                             const short* __restrict__ xm,
                                             const short* __restrict__ MT,
                                             const float* __restrict__ bo,
                                             float* __restrict__ out)
{
    int tid = threadIdx.x, w = tid >> 6, lane = tid & 63;
    int ln = lane & 15, qd = lane >> 4;
    int pw = blockIdx.x * 64 + w * 16;
    int b = pw >> 14, n0 = pw & (NPX - 1);

    f32x4 acc[1][4];
    acc_biasM<4, 1>(acc, bo);
    gemmM<64, 4, 1>(v + (size_t)pw * 64, 64, MT + b * 4096, acc);

#pragma unroll
    for (int t = 0; t < 4; ++t) {
        int c = t * 16 + ln;
        f32x4 o;
#pragma unroll
        for (int r = 0; r < 4; ++r)
            o[r] = acc[0][t][r] + h2f(xm[(size_t)(pw + qd * 4 + r) * 64 + c]);
        *reinterpret_cast<f32x4*>(out + ((size_t)b * 64 + c) * NPX + n0 + qd * 4) = o;
    }
}

// ---------------------------------------------------------------------------
extern "C" void kernel_launch(void* const* d_in, const int* in_sizes, int n_in,
                              void* d_out, int out_size, void* d_ws, size_t ws_size,
                              hipStream_t stream)
{
    const float* x    = (const float*)d_in[0];
    const float* sem  = (const float*)d_in[1];
    const float* wa   = (const float*)d_in[2];
    const float* ba   = (const float*)d_in[3];
    const float* wb   = (const float*)d_in[4];
    const float* bbv  = (const float*)d_in[5];
    const float* in_w = (const float*)d_in[6];
    const float* in_b = (const float*)d_in[7];
    const float* w1   = (const float*)d_in[8];
    const float* b1   = (const float*)d_in[9];
    const float* g1   = (const float*)d_in[10];
    const float* be1  = (const float*)d_in[11];
    const float* w2   = (const float*)d_in[12];
    const float* b2   = (const float*)d_in[13];
    const float* g2   = (const float*)d_in[14];
    const float* be2  = (const float*)d_in[15];
    const float* w3   = (const float*)d_in[16];
    const float* b3   = (const float*)d_in[17];
    const float* wq   = (const float*)d_in[18];
    const float* bq   = (const float*)d_in[19];
    const float* wk   = (const float*)d_in[20];
    const float* bk   = (const float*)d_in[21];
    const float* wv   = (const float*)d_in[22];
    const float* bv   = (const float*)d_in[23];
    const float* wo   = (const float*)d_in[24];
    const float* bo   = (const float*)d_in[25];
    const float* rescale = (const float*)d_in[26];

    char* wsb = (char*)d_ws;
    short* wt   = (short*)wsb;                                 // 53248 shorts
    short* kpx  = (short*)(wsb + (1u << 20));                  // 8 MB  [n][64] fp16
    short* vpx  = (short*)(wsb + (1u << 20) + (8u << 20));     // 8 MB
    short* xmp  = (short*)(wsb + (1u << 20) + (16u << 20));    // 8 MB
    short* qpx  = (short*)(wsb + (1u << 20) + (24u << 20));    // 8 MB
    float* gram = (float*)(wsb + (1u << 20) + (32u << 20));    // 4096 f32
    float* nsq  = gram + 4096;                                 // 512 f32
    short* MT   = (short*)(nsq + 512);                         // 16384 shorts

    dim3 blk(256);
    k_prep<<<dim3(208), blk, 0, stream>>>(wa, wb, in_w, w1, w2, w3, wq, wk, wv, wt);
    hipMemsetAsync(gram, 0, (4096 + 512) * sizeof(float), stream);
    k_main<<<dim3(1024), blk, 0, stream>>>(x, sem, ba, bbv, in_b, bk, bv,
                                           b1, g1, be1, b2, g2, be2, b3, bq,
                                           wt, kpx, vpx, xmp, qpx);
    k_gram<<<dim3(512), blk, 0, stream>>>(qpx, kpx, gram, nsq);
    k_attnM<<<dim3(4), blk, 0, stream>>>(gram, nsq, rescale, wo, MT);
    k_out<<<dim3(1024), blk, 0, stream>>>(vpx, xmp, MT, bo, (float*)d_out);
}